// Round 1
// baseline (311.645 us; speedup 1.0000x reference)
//
#include <hip/hip_runtime.h>
#include <math.h>

#define B 16
#define A 3
#define W 128
#define HW 16384          // 128*128
#define NCH 255
#define NCLS 80
#define NCAND 49152       // HW*A
#define K 100
#define CHUNK 2048
#define NCHUNK 24         // NCAND / CHUNK
#define CAND2 2400        // NCHUNK*K
#define SORT2 4096

__device__ __forceinline__ float sigmoidf_(float v) {
    return 1.0f / (1.0f + expf(-v));
}

__device__ __forceinline__ bool pair_before(float sa, int ia, float sb, int ib) {
    // "a comes before b" in descending-score, ascending-index order
    return (sa > sb) || (sa == sb && ia < ib);
}

// ---------------- Kernel 1: per-candidate masked score --------------------
__global__ __launch_bounds__(256) void k_scores(const float* __restrict__ x,
                                                float* __restrict__ scores) {
    int t = blockIdx.x * 256 + threadIdx.x;   // [0, B*A*HW)
    int b = t / (A * HW);
    int r = t - b * (A * HW);
    int a = r / HW;
    int hw = r - a * HW;
    const float* base = x + (size_t)(b * NCH + a * 85) * HW + hw;
    float obj_logit = base[4 * HW];
    float m = base[5 * HW];
    #pragma unroll
    for (int c = 1; c < NCLS; ++c) {
        m = fmaxf(m, base[(5 + c) * HW]);
    }
    float obj = sigmoidf_(obj_logit);
    float cls = sigmoidf_(m);          // sigmoid monotone: max(sigmoid) = sigmoid(max)
    float score = obj * cls;
    bool valid = (obj >= 0.5f) && (score >= 0.05f);
    // reference flat index = (y*W + x)*A + a = hw*A + a
    scores[(size_t)b * NCAND + hw * A + a] = valid ? score : -1.0f;
}

// ---------------- Kernel 2: per-chunk top-100 via bitonic sort ------------
__global__ __launch_bounds__(256) void k_chunk_topk(const float* __restrict__ scores,
                                                    float* __restrict__ cand_s,
                                                    int* __restrict__ cand_i) {
    __shared__ float s[CHUNK];
    __shared__ int id[CHUNK];
    int b = blockIdx.x / NCHUNK;
    int chunk = blockIdx.x % NCHUNK;
    int tid = threadIdx.x;
    for (int i = tid; i < CHUNK; i += 256) {
        int n = chunk * CHUNK + i;
        s[i] = scores[(size_t)b * NCAND + n];
        id[i] = n;
    }
    __syncthreads();
    for (int k = 2; k <= CHUNK; k <<= 1) {
        for (int j = k >> 1; j > 0; j >>= 1) {
            for (int i = tid; i < CHUNK; i += 256) {
                int ixj = i ^ j;
                if (ixj > i) {
                    bool desc = ((i & k) == 0);
                    float si = s[i], sj = s[ixj];
                    int ii = id[i], ij = id[ixj];
                    bool sw = desc ? pair_before(sj, ij, si, ii)
                                   : pair_before(si, ii, sj, ij);
                    if (sw) { s[i] = sj; s[ixj] = si; id[i] = ij; id[ixj] = ii; }
                }
            }
            __syncthreads();
        }
    }
    if (tid < K) {
        cand_s[(b * NCHUNK + chunk) * K + tid] = s[tid];
        cand_i[(b * NCHUNK + chunk) * K + tid] = id[tid];
    }
}

// ---------------- Kernel 3: per-image merge, decode, NMS, write -----------
__global__ __launch_bounds__(512) void k_final(const float* __restrict__ x,
                                               const float* __restrict__ anchors,
                                               const float* __restrict__ cand_s,
                                               const int* __restrict__ cand_i,
                                               float* __restrict__ out) {
    __shared__ float s[SORT2];
    __shared__ int id[SORT2];
    __shared__ float bx[K][4];
    __shared__ float area[K];
    __shared__ int label[K];
    __shared__ int keep[K];
    int b = blockIdx.x;
    int tid = threadIdx.x;

    for (int i = tid; i < SORT2; i += 512) {
        if (i < CAND2) {
            s[i] = cand_s[b * CAND2 + i];
            id[i] = cand_i[b * CAND2 + i];
        } else {
            s[i] = -3.0f;            // below any real masked score (>= -1)
            id[i] = 0x7FFFFFFF;
        }
    }
    __syncthreads();

    // bitonic sort 4096, descending (score desc, index asc)
    for (int k = 2; k <= SORT2; k <<= 1) {
        for (int j = k >> 1; j > 0; j >>= 1) {
            for (int i = tid; i < SORT2; i += 512) {
                int ixj = i ^ j;
                if (ixj > i) {
                    bool desc = ((i & k) == 0);
                    float si = s[i], sj = s[ixj];
                    int ii = id[i], ij = id[ixj];
                    bool sw = desc ? pair_before(sj, ij, si, ii)
                                   : pair_before(si, ii, sj, ij);
                    if (sw) { s[i] = sj; s[ixj] = si; id[i] = ij; id[ixj] = ii; }
                }
            }
            __syncthreads();
        }
    }

    // decode the top-K candidates (re-read the 85 channels; tiny)
    if (tid < K) {
        int n = id[tid];
        float sc = s[tid];
        int a = n % A;
        int hw = n / A;
        int cx = hw % W;
        int cy = hw / W;
        const float* base = x + (size_t)(b * NCH + a * 85) * HW + hw;
        float tx = base[0];
        float ty = base[HW];
        float tw = base[2 * HW];
        float th = base[3 * HW];
        float bcx = (sigmoidf_(tx) + (float)cx) / 128.0f;
        float bcy = (sigmoidf_(ty) + (float)cy) / 128.0f;
        float bw = fminf(fmaxf(expf(tw) * anchors[a * 2 + 0], 0.0f), 2.0f);
        float bh = fminf(fmaxf(expf(th) * anchors[a * 2 + 1], 0.0f), 2.0f);
        float x1 = bcx - 0.5f * bw;
        float y1 = bcy - 0.5f * bh;
        float x2 = x1 + bw;          // before clipping, as in reference
        float y2 = y1 + bh;
        x1 = fminf(fmaxf(x1, 0.0f), 1.0f);
        y1 = fminf(fmaxf(y1, 0.0f), 1.0f);
        x2 = fminf(fmaxf(x2, 0.0f), 1.0f);
        y2 = fminf(fmaxf(y2, 0.0f), 1.0f);
        bx[tid][0] = x1; bx[tid][1] = y1; bx[tid][2] = x2; bx[tid][3] = y2;
        area[tid] = fmaxf(x2 - x1, 0.0f) * fmaxf(y2 - y1, 0.0f);
        // argmax over class logits (monotone sigmoid => same argmax, first-max wins)
        float m = base[5 * HW];
        int lab = 0;
        for (int c = 1; c < NCLS; ++c) {
            float v = base[(5 + c) * HW];
            if (v > m) { m = v; lab = c; }
        }
        label[tid] = lab;
        keep[tid] = (sc > 0.0f) ? 1 : 0;
    }
    __syncthreads();

    // greedy NMS: iterate rows sequentially, one thread per column
    for (int i = 0; i < K; ++i) {
        bool ki = keep[i] != 0;
        if (ki && tid > i && tid < K && keep[tid]) {
            float lx = fmaxf(bx[i][0], bx[tid][0]);
            float ly = fmaxf(bx[i][1], bx[tid][1]);
            float rx = fminf(bx[i][2], bx[tid][2]);
            float ry = fminf(bx[i][3], bx[tid][3]);
            float iw = fmaxf(rx - lx, 0.0f);
            float ih = fmaxf(ry - ly, 0.0f);
            float inter = iw * ih;
            float uni = area[i] + area[tid] - inter;
            float iou = inter / fmaxf(uni, 1e-12f);
            if (iou > 0.7f) keep[tid] = 0;
        }
        __syncthreads();
    }

    // write outputs: boxes | scores | labels | keep (all float32, flat)
    if (tid < K) {
        int kp = keep[tid];
        float sc = s[tid];
        float* ob = out + (size_t)b * K * 4;
        float* osc = out + (size_t)B * K * 4;
        float* olab = osc + (size_t)B * K;
        float* okp = olab + (size_t)B * K;
        ob[tid * 4 + 0] = kp ? bx[tid][0] : 0.0f;
        ob[tid * 4 + 1] = kp ? bx[tid][1] : 0.0f;
        ob[tid * 4 + 2] = kp ? bx[tid][2] : 0.0f;
        ob[tid * 4 + 3] = kp ? bx[tid][3] : 0.0f;
        osc[b * K + tid] = kp ? sc : 0.0f;
        olab[b * K + tid] = kp ? (float)label[tid] : -1.0f;
        okp[b * K + tid] = kp ? 1.0f : 0.0f;
    }
}

extern "C" void kernel_launch(void* const* d_in, const int* in_sizes, int n_in,
                              void* d_out, int out_size, void* d_ws, size_t ws_size,
                              hipStream_t stream) {
    const float* x = (const float*)d_in[0];
    const float* anchors = (const float*)d_in[1];
    float* out = (float*)d_out;

    float* scores = (float*)d_ws;                        // B*NCAND floats (3.1 MB)
    float* cand_s = scores + (size_t)B * NCAND;          // B*2400 floats
    int* cand_i = (int*)(cand_s + (size_t)B * CAND2);    // B*2400 ints

    k_scores<<<(B * A * HW) / 256, 256, 0, stream>>>(x, scores);
    k_chunk_topk<<<B * NCHUNK, 256, 0, stream>>>(scores, cand_s, cand_i);
    k_final<<<B, 512, 0, stream>>>(x, anchors, cand_s, cand_i, out);
}

// Round 2
// 130.248 us; speedup vs baseline: 2.3927x; 2.3927x over previous
//
#include <hip/hip_runtime.h>
#include <math.h>

#define B 16
#define A 3
#define W 128
#define HW 16384          // 128*128
#define NCH 255
#define NCLS 80
#define NCAND 49152       // HW*A
#define K 100
#define NBINS 4096
#define CAP 512

__device__ __forceinline__ float sigmoidf_(float v) {
    return 1.0f / (1.0f + expf(-v));
}

__device__ __forceinline__ bool pair_before(float sa, int ia, float sb, int ib) {
    // "a comes before b" in descending-score, ascending-index order
    return (sa > sb) || (sa == sb && ia < ib);
}

// ---- Kernel 1: masked score per candidate + per-image score histogram ----
// grid: B*A*16 blocks (each block = 1024 consecutive hw of one (b,a) plane)
__global__ __launch_bounds__(256) void k_scores(const float* __restrict__ x,
                                                float* __restrict__ scores,
                                                unsigned int* __restrict__ hist) {
    __shared__ unsigned int lh[NBINS];
    int blk = blockIdx.x;
    int b = blk / 48;
    int rem = blk % 48;
    int a = rem / 16;
    int seg = rem % 16;
    int hw = seg * 1024 + threadIdx.x * 4;

    for (int i = threadIdx.x; i < NBINS; i += 256) lh[i] = 0;
    __syncthreads();

    const float* base = x + (size_t)(b * NCH + a * 85) * HW + hw;
    float4 o4 = *(const float4*)(base + 4 * HW);
    float4 m4 = *(const float4*)(base + 5 * HW);
    #pragma unroll
    for (int c = 1; c < NCLS; ++c) {
        float4 v = *(const float4*)(base + (5 + c) * HW);
        m4.x = fmaxf(m4.x, v.x);
        m4.y = fmaxf(m4.y, v.y);
        m4.z = fmaxf(m4.z, v.z);
        m4.w = fmaxf(m4.w, v.w);
    }
    float ol[4] = {o4.x, o4.y, o4.z, o4.w};
    float ml[4] = {m4.x, m4.y, m4.z, m4.w};
    float out[4];
    #pragma unroll
    for (int l = 0; l < 4; ++l) {
        float obj = sigmoidf_(ol[l]);
        float cls = sigmoidf_(ml[l]);      // sigmoid monotone: max(sig)=sig(max)
        float sc = obj * cls;
        bool valid = (obj >= 0.5f) && (sc >= 0.05f);
        float ms = valid ? sc : -1.0f;
        out[l] = ms;
        if (ms > 0.0f) {
            int bin = (int)(ms * (float)NBINS);
            bin = bin > NBINS - 1 ? NBINS - 1 : bin;
            atomicAdd(&lh[bin], 1u);
        }
    }
    // storage layout [b][a][hw] for coalesced float4 I/O
    *(float4*)(scores + (size_t)b * NCAND + a * HW + hw) =
        make_float4(out[0], out[1], out[2], out[3]);

    __syncthreads();
    for (int i = threadIdx.x; i < NBINS; i += 256)
        if (lh[i]) atomicAdd(&hist[b * NBINS + i], lh[i]);
}

// ---- Kernel 2: per-image threshold bin (smallest bin with count(>=bin) >= K)
__global__ __launch_bounds__(256) void k_select(const unsigned int* __restrict__ hist,
                                                int* __restrict__ thr) {
    __shared__ unsigned int h[NBINS];
    __shared__ unsigned int suf[256];
    __shared__ int tstar;
    int b = blockIdx.x;
    int tid = threadIdx.x;
    for (int i = tid; i < NBINS; i += 256) h[i] = hist[b * NBINS + i];
    if (tid == 0) tstar = -1;
    __syncthreads();
    unsigned int s = 0;
    #pragma unroll
    for (int j = 0; j < 16; ++j) s += h[tid * 16 + j];
    suf[tid] = s;
    __syncthreads();
    for (int off = 1; off < 256; off <<= 1) {
        unsigned int v = suf[tid];
        unsigned int add = (tid + off < 256) ? suf[tid + off] : 0u;
        __syncthreads();
        suf[tid] = v + add;
        __syncthreads();
    }
    // find max t with suf[t] >= K (suf is non-increasing)
    if (suf[tid] >= K && (tid == 255 || suf[tid + 1] < K)) tstar = tid;
    __syncthreads();
    if (tid == 0) {
        int t = tstar;
        int result = 0;
        if (t >= 0) {
            unsigned int running = (t < 255) ? suf[t + 1] : 0u;
            result = t * 16;
            for (int bin = t * 16 + 15; bin >= t * 16; --bin) {
                running += h[bin];
                if (running >= K) { result = bin; break; }
            }
        }
        thr[b] = result;
    }
}

// ---- Kernel 3: compact candidates with bin >= thr --------------------------
__global__ __launch_bounds__(256) void k_compact(const float* __restrict__ scores,
                                                 const int* __restrict__ thr,
                                                 unsigned int* __restrict__ cnt,
                                                 float* __restrict__ cs,
                                                 int* __restrict__ ci) {
    int blk = blockIdx.x;       // B*48
    int b = blk / 48;
    int off = (blk % 48) * 1024 + threadIdx.x * 4;   // storage offset a*HW+hw
    float4 v = *(const float4*)(scores + (size_t)b * NCAND + off);
    int t = thr[b];
    float sv[4] = {v.x, v.y, v.z, v.w};
    #pragma unroll
    for (int l = 0; l < 4; ++l) {
        float s = sv[l];
        if (s > 0.0f && (int)(s * (float)NBINS) >= t) {
            unsigned int p = atomicAdd(&cnt[b], 1u);
            if (p < CAP) {
                int so = off + l;
                int aa = so >> 14;          // / HW
                int hh = so & (HW - 1);     // % HW
                cs[b * CAP + p] = s;
                ci[b * CAP + p] = hh * A + aa;   // reference flat index
            }
        }
    }
}

// ---- Kernel 4: per-image sort-512, decode top-100, bitmask NMS, write ------
__global__ __launch_bounds__(256) void k_final2(const float* __restrict__ x,
                                                const float* __restrict__ anchors,
                                                const unsigned int* __restrict__ cnt,
                                                const float* __restrict__ cs,
                                                const int* __restrict__ ci,
                                                float* __restrict__ out) {
    __shared__ float s[CAP];
    __shared__ int id[CAP];
    __shared__ float bx[K][4];
    __shared__ float area[K];
    __shared__ float pv[K][16];
    __shared__ int pi[K][16];
    __shared__ int label[K];
    __shared__ unsigned int sup[K][4];
    __shared__ unsigned int keepw[4];
    int b = blockIdx.x;
    int tid = threadIdx.x;
    int n = (int)cnt[b];
    if (n > CAP) n = CAP;

    for (int i = tid; i < CAP; i += 256) {
        if (i < n) {
            s[i] = cs[b * CAP + i];
            id[i] = ci[b * CAP + i];
        } else {
            s[i] = -3.0f;
            id[i] = 0x7FFFFFFF;
        }
    }
    if (tid < 4) keepw[tid] = 0u;
    for (int i = tid; i < K * 4; i += 256) ((unsigned int*)sup)[i] = 0u;
    __syncthreads();

    // bitonic sort CAP=512 (score desc, index asc)
    for (int k = 2; k <= CAP; k <<= 1) {
        for (int j = k >> 1; j > 0; j >>= 1) {
            for (int i = tid; i < CAP; i += 256) {
                int ixj = i ^ j;
                if (ixj > i) {
                    bool desc = ((i & k) == 0);
                    float si = s[i], sj = s[ixj];
                    int ii = id[i], ij = id[ixj];
                    bool sw = desc ? pair_before(sj, ij, si, ii)
                                   : pair_before(si, ii, sj, ij);
                    if (sw) { s[i] = sj; s[ixj] = si; id[i] = ij; id[ixj] = ii; }
                }
            }
            __syncthreads();
        }
    }

    // decode boxes for valid top-K
    if (tid < K) {
        float sc = s[tid];
        if (sc > 0.0f) {
            int nidx = id[tid];
            int a = nidx % A;
            int hw = nidx / A;
            int cx = hw % W;
            int cy = hw / W;
            const float* base = x + (size_t)(b * NCH + a * 85) * HW + hw;
            float tx = base[0];
            float ty = base[HW];
            float tw = base[2 * HW];
            float th = base[3 * HW];
            float bcx = (sigmoidf_(tx) + (float)cx) / 128.0f;
            float bcy = (sigmoidf_(ty) + (float)cy) / 128.0f;
            float bw = fminf(fmaxf(expf(tw) * anchors[a * 2 + 0], 0.0f), 2.0f);
            float bh = fminf(fmaxf(expf(th) * anchors[a * 2 + 1], 0.0f), 2.0f);
            float x1 = bcx - 0.5f * bw;
            float y1 = bcy - 0.5f * bh;
            float x2 = x1 + bw;
            float y2 = y1 + bh;
            x1 = fminf(fmaxf(x1, 0.0f), 1.0f);
            y1 = fminf(fmaxf(y1, 0.0f), 1.0f);
            x2 = fminf(fmaxf(x2, 0.0f), 1.0f);
            y2 = fminf(fmaxf(y2, 0.0f), 1.0f);
            bx[tid][0] = x1; bx[tid][1] = y1; bx[tid][2] = x2; bx[tid][3] = y2;
            area[tid] = fmaxf(x2 - x1, 0.0f) * fmaxf(y2 - y1, 0.0f);
            atomicOr(&keepw[tid >> 5], 1u << (tid & 31));
        } else {
            bx[tid][0] = 0.0f; bx[tid][1] = 0.0f; bx[tid][2] = 0.0f; bx[tid][3] = 0.0f;
            area[tid] = 0.0f;
        }
    }

    // class argmax, parallel over (cand, class-group-of-5)
    for (int p = tid; p < K * 16; p += 256) {
        int c = p >> 4, g = p & 15;
        float bv = -1e30f; int bi = 0;
        if (s[c] > 0.0f) {
            int nidx = id[c];
            int a = nidx % A;
            int hw = nidx / A;
            const float* cb = x + (size_t)(b * NCH + a * 85 + 5) * HW + hw;
            #pragma unroll
            for (int q = 0; q < 5; ++q) {
                int cls = g * 5 + q;
                float v = cb[(size_t)cls * HW];
                if (v > bv) { bv = v; bi = cls; }
            }
        }
        pv[c][g] = bv; pi[c][g] = bi;
    }
    __syncthreads();
    if (tid < K) {
        float bv = pv[tid][0]; int bi = pi[tid][0];
        #pragma unroll
        for (int g = 1; g < 16; ++g) {
            if (pv[tid][g] > bv) { bv = pv[tid][g]; bi = pi[tid][g]; }
        }
        label[tid] = bi;
    }
    __syncthreads();

    // IoU suppression bitmasks (only valid pairs, j > i)
    for (int p = tid; p < K * K; p += 256) {
        int i = p / K, j = p % K;
        if (j > i && s[i] > 0.0f && s[j] > 0.0f) {
            float lx = fmaxf(bx[i][0], bx[j][0]);
            float ly = fmaxf(bx[i][1], bx[j][1]);
            float rx = fminf(bx[i][2], bx[j][2]);
            float ry = fminf(bx[i][3], bx[j][3]);
            float iw = fmaxf(rx - lx, 0.0f);
            float ih = fmaxf(ry - ly, 0.0f);
            float inter = iw * ih;
            float uni = area[i] + area[j] - inter;
            float iou = inter / fmaxf(uni, 1e-12f);
            if (iou > 0.7f) atomicOr(&sup[i][j >> 5], 1u << (j & 31));
        }
    }
    __syncthreads();

    // greedy scan on one thread (register bit-ops)
    if (tid == 0) {
        unsigned int kw0 = keepw[0], kw1 = keepw[1], kw2 = keepw[2], kw3 = keepw[3];
        for (int i = 0; i < K; ++i) {
            unsigned int kwi = (i < 32) ? kw0 : (i < 64) ? kw1 : (i < 96) ? kw2 : kw3;
            if ((kwi >> (i & 31)) & 1u) {
                kw0 &= ~sup[i][0];
                kw1 &= ~sup[i][1];
                kw2 &= ~sup[i][2];
                kw3 &= ~sup[i][3];
            }
        }
        keepw[0] = kw0; keepw[1] = kw1; keepw[2] = kw2; keepw[3] = kw3;
    }
    __syncthreads();

    // write outputs: boxes | scores | labels | keep (all float32, flat)
    if (tid < K) {
        int kp = (keepw[tid >> 5] >> (tid & 31)) & 1u;
        float sc = s[tid];
        float* ob = out + (size_t)b * K * 4;
        float* osc = out + (size_t)B * K * 4;
        float* olab = osc + (size_t)B * K;
        float* okp = olab + (size_t)B * K;
        ob[tid * 4 + 0] = kp ? bx[tid][0] : 0.0f;
        ob[tid * 4 + 1] = kp ? bx[tid][1] : 0.0f;
        ob[tid * 4 + 2] = kp ? bx[tid][2] : 0.0f;
        ob[tid * 4 + 3] = kp ? bx[tid][3] : 0.0f;
        osc[b * K + tid] = kp ? sc : 0.0f;
        olab[b * K + tid] = kp ? (float)label[tid] : -1.0f;
        okp[b * K + tid] = kp ? 1.0f : 0.0f;
    }
}

extern "C" void kernel_launch(void* const* d_in, const int* in_sizes, int n_in,
                              void* d_out, int out_size, void* d_ws, size_t ws_size,
                              hipStream_t stream) {
    const float* x = (const float*)d_in[0];
    const float* anchors = (const float*)d_in[1];
    float* out = (float*)d_out;

    // workspace layout (16B-aligned chunks first)
    float* scores = (float*)d_ws;                                   // B*NCAND f32 (3 MB)
    unsigned int* hist = (unsigned int*)(scores + (size_t)B * NCAND); // B*NBINS u32 (256 KB)
    float* cand_s = (float*)(hist + (size_t)B * NBINS);             // B*CAP f32
    int* cand_i = (int*)(cand_s + (size_t)B * CAP);                 // B*CAP i32
    int* thr = (int*)(cand_i + (size_t)B * CAP);                    // B i32
    unsigned int* cnt = (unsigned int*)(thr + B);                   // B u32

    hipMemsetAsync(hist, 0, (size_t)B * NBINS * sizeof(unsigned int), stream);
    hipMemsetAsync(cnt, 0, (size_t)B * sizeof(unsigned int), stream);

    k_scores<<<B * A * 16, 256, 0, stream>>>(x, scores, hist);
    k_select<<<B, 256, 0, stream>>>(hist, thr);
    k_compact<<<B * 48, 256, 0, stream>>>(scores, thr, cnt, cand_s, cand_i);
    k_final2<<<B, 256, 0, stream>>>(x, anchors, cnt, cand_s, cand_i, out);
}

// Round 3
// 70.746 us; speedup vs baseline: 4.4051x; 1.8411x over previous
//
#include <hip/hip_runtime.h>
#include <math.h>

#define B 16
#define A 3
#define W 128
#define HW 16384          // 128*128
#define NCH 255
#define NCLS 80
#define NCAND 49152       // HW*A
#define K 100
#define NBINS 4096
#define CAP 1024

__device__ __forceinline__ float sigmoidf_(float v) {
    return 1.0f / (1.0f + expf(-v));
}

__device__ __forceinline__ bool pair_before(float sa, int ia, float sb, int ib) {
    // "a comes before b" in descending-score, ascending-index order
    return (sa > sb) || (sa == sb && ia < ib);
}

// ---- Kernel 1: pure-streaming masked score + class argmax -----------------
// grid: B*A*HW/4/256 = 768 blocks; each thread owns 4 consecutive hw cells
__global__ __launch_bounds__(256) void k_scores(const float* __restrict__ x,
                                                float* __restrict__ scores,
                                                unsigned char* __restrict__ labels) {
    int t = blockIdx.x * 256 + threadIdx.x;
    int b = t / (A * HW / 4);
    int r = t - b * (A * HW / 4);
    int a = r / (HW / 4);
    int q = r - a * (HW / 4);
    int hw = q * 4;
    const float* base = x + (size_t)(b * NCH + a * 85) * HW + hw;

    float4 o4 = *(const float4*)(base + 4 * HW);
    float4 m4 = *(const float4*)(base + 5 * HW);
    int amx = 0, amy = 0, amz = 0, amw = 0;
    #pragma unroll
    for (int c = 1; c < NCLS; ++c) {
        float4 v = *(const float4*)(base + (5 + c) * HW);
        bool gx = v.x > m4.x; amx = gx ? c : amx; m4.x = gx ? v.x : m4.x;
        bool gy = v.y > m4.y; amy = gy ? c : amy; m4.y = gy ? v.y : m4.y;
        bool gz = v.z > m4.z; amz = gz ? c : amz; m4.z = gz ? v.z : m4.z;
        bool gw = v.w > m4.w; amw = gw ? c : amw; m4.w = gw ? v.w : m4.w;
    }
    float ol[4] = {o4.x, o4.y, o4.z, o4.w};
    float ml[4] = {m4.x, m4.y, m4.z, m4.w};
    float outv[4];
    #pragma unroll
    for (int l = 0; l < 4; ++l) {
        float obj = sigmoidf_(ol[l]);
        float cls = sigmoidf_(ml[l]);      // sigmoid monotone: max(sig)=sig(max)
        float sc = obj * cls;
        bool valid = (obj >= 0.5f) && (sc >= 0.05f);
        outv[l] = valid ? sc : -1.0f;
    }
    // storage layout [b][a][hw] for coalesced I/O
    size_t off = (size_t)b * NCAND + a * HW + hw;
    *(float4*)(scores + off) = make_float4(outv[0], outv[1], outv[2], outv[3]);
    *(uchar4*)(labels + off) = make_uchar4((unsigned char)amx, (unsigned char)amy,
                                           (unsigned char)amz, (unsigned char)amw);
}

// ---- Kernel 2: per-image fused hist+select+compact+rank-topk+decode+NMS ---
__global__ __launch_bounds__(1024) void k_final3(const float* __restrict__ x,
                                                 const float* __restrict__ anchors,
                                                 const float* __restrict__ scores,
                                                 const unsigned char* __restrict__ labels,
                                                 float* __restrict__ out) {
    __shared__ unsigned int hist[NBINS];      // 16 KB
    __shared__ unsigned int suf[1024];        // 4 KB
    __shared__ int tstar, sh_thr;
    __shared__ unsigned int sh_cnt;
    __shared__ float cs[CAP];                 // 4 KB
    __shared__ int ci[CAP];                   // 4 KB
    __shared__ float ts[K];
    __shared__ int tix[K];
    __shared__ float bx[K][4];
    __shared__ float area[K];
    __shared__ int lab[K];
    __shared__ unsigned int sup[K][4];
    __shared__ unsigned int keepw[4];

    int b = blockIdx.x;
    int tid = threadIdx.x;
    const float* sb = scores + (size_t)b * NCAND;

    for (int i = tid; i < NBINS; i += 1024) hist[i] = 0;
    if (tid == 0) { tstar = -1; sh_thr = 0; sh_cnt = 0; }
    if (tid < 4) keepw[tid] = 0u;
    for (int i = tid; i < K * 4; i += 1024) ((unsigned int*)sup)[i] = 0u;
    if (tid < K) { ts[tid] = -3.0f; tix[tid] = 0x7FFFFFFF; }
    __syncthreads();

    // pass 1: histogram of valid scores
    #pragma unroll
    for (int it = 0; it < 12; ++it) {
        int o = (it * 1024 + tid) * 4;
        float4 v = *(const float4*)(sb + o);
        float sv[4] = {v.x, v.y, v.z, v.w};
        #pragma unroll
        for (int l = 0; l < 4; ++l) {
            float s = sv[l];
            if (s > 0.0f) {
                int bin = (int)(s * (float)NBINS);
                bin = bin > NBINS - 1 ? NBINS - 1 : bin;
                atomicAdd(&hist[bin], 1u);
            }
        }
    }
    __syncthreads();

    // coarse (x4) suffix scan over 1024 entries
    unsigned int acc = hist[tid * 4] + hist[tid * 4 + 1] +
                       hist[tid * 4 + 2] + hist[tid * 4 + 3];
    suf[tid] = acc;
    __syncthreads();
    for (int off = 1; off < 1024; off <<= 1) {
        unsigned int add = (tid + off < 1024) ? suf[tid + off] : 0u;
        __syncthreads();
        suf[tid] += add;
        __syncthreads();
    }
    if (suf[tid] >= K && (tid == 1023 || suf[tid + 1] < K)) tstar = tid;
    __syncthreads();
    if (tid == 0 && tstar >= 0) {
        int t = tstar;
        unsigned int running = (t < 1023) ? suf[t + 1] : 0u;
        int result = t * 4;
        for (int bin = t * 4 + 3; bin >= t * 4; --bin) {
            running += hist[bin];
            if (running >= K) { result = bin; break; }
        }
        sh_thr = result;
    }
    __syncthreads();

    // pass 2: compact survivors (bin >= thr) into LDS
    int thr = sh_thr;
    #pragma unroll
    for (int it = 0; it < 12; ++it) {
        int o = (it * 1024 + tid) * 4;
        float4 v = *(const float4*)(sb + o);
        float sv[4] = {v.x, v.y, v.z, v.w};
        #pragma unroll
        for (int l = 0; l < 4; ++l) {
            float s = sv[l];
            if (s > 0.0f && (int)(s * (float)NBINS) >= thr) {
                unsigned int p = atomicAdd(&sh_cnt, 1u);
                if (p < CAP) {
                    int so = o + l;                 // storage offset a*HW+hw
                    int aa = so >> 14;
                    int hh = so & (HW - 1);
                    cs[p] = s;
                    ci[p] = hh * A + aa;            // reference flat index
                }
            }
        }
    }
    __syncthreads();
    int n = (int)sh_cnt; if (n > CAP) n = CAP;

    // one-pass rank select: rank = #pairs strictly before me
    if (tid < n) {
        float s0 = cs[tid]; int i0 = ci[tid];
        int rank = 0;
        for (int j = 0; j < n; ++j)
            rank += pair_before(cs[j], ci[j], s0, i0) ? 1 : 0;
        if (rank < K) { ts[rank] = s0; tix[rank] = i0; }
    }
    __syncthreads();

    // decode boxes + label for valid top-K
    if (tid < K && ts[tid] > 0.0f) {
        int nidx = tix[tid];
        int a = nidx % A;
        int hw = nidx / A;
        int cx = hw % W;
        int cy = hw / W;
        const float* base = x + (size_t)(b * NCH + a * 85) * HW + hw;
        float tx = base[0];
        float ty = base[HW];
        float tw = base[2 * HW];
        float th = base[3 * HW];
        float bcx = (sigmoidf_(tx) + (float)cx) / 128.0f;
        float bcy = (sigmoidf_(ty) + (float)cy) / 128.0f;
        float bw = fminf(fmaxf(expf(tw) * anchors[a * 2 + 0], 0.0f), 2.0f);
        float bh = fminf(fmaxf(expf(th) * anchors[a * 2 + 1], 0.0f), 2.0f);
        float x1 = bcx - 0.5f * bw;
        float y1 = bcy - 0.5f * bh;
        float x2 = x1 + bw;
        float y2 = y1 + bh;
        x1 = fminf(fmaxf(x1, 0.0f), 1.0f);
        y1 = fminf(fmaxf(y1, 0.0f), 1.0f);
        x2 = fminf(fmaxf(x2, 0.0f), 1.0f);
        y2 = fminf(fmaxf(y2, 0.0f), 1.0f);
        bx[tid][0] = x1; bx[tid][1] = y1; bx[tid][2] = x2; bx[tid][3] = y2;
        area[tid] = fmaxf(x2 - x1, 0.0f) * fmaxf(y2 - y1, 0.0f);
        lab[tid] = (int)labels[(size_t)b * NCAND + a * HW + hw];
        atomicOr(&keepw[tid >> 5], 1u << (tid & 31));
    }
    __syncthreads();

    // IoU suppression bitmasks (j > i, both valid)
    for (int p = tid; p < K * K; p += 1024) {
        int i = p / K, j = p % K;
        if (j > i && ts[i] > 0.0f && ts[j] > 0.0f) {
            float lx = fmaxf(bx[i][0], bx[j][0]);
            float ly = fmaxf(bx[i][1], bx[j][1]);
            float rx = fminf(bx[i][2], bx[j][2]);
            float ry = fminf(bx[i][3], bx[j][3]);
            float iw = fmaxf(rx - lx, 0.0f);
            float ih = fmaxf(ry - ly, 0.0f);
            float inter = iw * ih;
            float uni = area[i] + area[j] - inter;
            float iou = inter / fmaxf(uni, 1e-12f);
            if (iou > 0.7f) atomicOr(&sup[i][j >> 5], 1u << (j & 31));
        }
    }
    __syncthreads();

    // greedy scan (register bit-ops, one thread)
    if (tid == 0) {
        unsigned int kw0 = keepw[0], kw1 = keepw[1], kw2 = keepw[2], kw3 = keepw[3];
        for (int i = 0; i < K; ++i) {
            unsigned int kwi = (i < 32) ? kw0 : (i < 64) ? kw1 : (i < 96) ? kw2 : kw3;
            if ((kwi >> (i & 31)) & 1u) {
                kw0 &= ~sup[i][0];
                kw1 &= ~sup[i][1];
                kw2 &= ~sup[i][2];
                kw3 &= ~sup[i][3];
            }
        }
        keepw[0] = kw0; keepw[1] = kw1; keepw[2] = kw2; keepw[3] = kw3;
    }
    __syncthreads();

    // write outputs: boxes | scores | labels | keep (all float32, flat)
    if (tid < K) {
        int kp = (keepw[tid >> 5] >> (tid & 31)) & 1u;
        float sc = ts[tid];
        float* ob = out + (size_t)b * K * 4;
        float* osc = out + (size_t)B * K * 4;
        float* olab = osc + (size_t)B * K;
        float* okp = olab + (size_t)B * K;
        ob[tid * 4 + 0] = kp ? bx[tid][0] : 0.0f;
        ob[tid * 4 + 1] = kp ? bx[tid][1] : 0.0f;
        ob[tid * 4 + 2] = kp ? bx[tid][2] : 0.0f;
        ob[tid * 4 + 3] = kp ? bx[tid][3] : 0.0f;
        osc[b * K + tid] = kp ? sc : 0.0f;
        olab[b * K + tid] = kp ? (float)lab[tid] : -1.0f;
        okp[b * K + tid] = kp ? 1.0f : 0.0f;
    }
}

extern "C" void kernel_launch(void* const* d_in, const int* in_sizes, int n_in,
                              void* d_out, int out_size, void* d_ws, size_t ws_size,
                              hipStream_t stream) {
    const float* x = (const float*)d_in[0];
    const float* anchors = (const float*)d_in[1];
    float* out = (float*)d_out;

    float* scores = (float*)d_ws;                                     // B*NCAND f32 (3 MB)
    unsigned char* labels = (unsigned char*)(scores + (size_t)B * NCAND); // B*NCAND u8

    k_scores<<<(B * A * HW / 4) / 256, 256, 0, stream>>>(x, scores, labels);
    k_final3<<<B, 1024, 0, stream>>>(x, anchors, scores, labels, out);
}